// Round 1
// baseline (826.664 us; speedup 1.0000x reference)
//
#include <hip/hip_runtime.h>
#include <math.h>

#define HL 32
#define WL 32
#define HH 512
#define WH 512
#define CF 128

// ws layout (floats):
//   params: [1024][8]   at offset 0        (cos, sin, inv2sx2, inv2sy2, inv2sr2, Rsq, -, -)
//   glr:    [1024][4]   at offset 8192     (guide_lr per cell, 3 ch + pad)
//   featT:  [1024][128] at offset 12288    (feat transposed to cell-major)

__global__ __launch_bounds__(256) void prep_kernel(
    const float* __restrict__ feat,   // [128][32][32]
    const float* __restrict__ guide,  // [3][512][512]
    const float* __restrict__ sx_raw,
    const float* __restrict__ sy_raw,
    const float* __restrict__ th_raw,
    const float* __restrict__ sr_raw,
    float* __restrict__ ws)
{
    const int gid = blockIdx.x * 256 + threadIdx.x;
    float* params = ws;             // [1024][8]
    float* glr    = ws + 8192;      // [1024][4]
    float* featT  = ws + 12288;     // [1024][128]

    // transpose feat: featT[cell][c] = feat[c][cell]  (write coalesced)
    if (gid < 1024 * 128) {
        const int cell = gid >> 7;
        const int c    = gid & 127;
        featT[gid] = feat[c * 1024 + cell];
    }

    if (gid < 1024) {
        const int u = gid >> 5, v = gid & 31;
        // bilinear downsample at SCALE=16 degenerates to 2x2 average at (16u+7, 16v+7)
        const int y0 = u * 16 + 7, x0 = v * 16 + 7;
        #pragma unroll
        for (int ch = 0; ch < 3; ++ch) {
            const float* g = guide + ch * (HH * WH);
            const float s = g[y0 * WH + x0] + g[y0 * WH + x0 + 1]
                          + g[(y0 + 1) * WH + x0] + g[(y0 + 1) * WH + x0 + 1];
            glr[gid * 4 + ch] = 0.25f * s;
        }
        glr[gid * 4 + 3] = 0.0f;

        const float sx = fmaxf(expf(sx_raw[gid]), 1e-6f);
        const float sy = fmaxf(expf(sy_raw[gid]), 1e-6f);
        const float th = 3.14159265358979323846f * tanhf(th_raw[gid]);
        const float sr = fmaxf(expf(sr_raw[gid]), 1e-6f);
        const float R  = fminf(fmaxf(2.0f * fmaxf(sx, sy), 1.0f), 4.0f);
        params[gid * 8 + 0] = cosf(th);
        params[gid * 8 + 1] = sinf(th);
        params[gid * 8 + 2] = 1.0f / (2.0f * sx * sx + 1e-8f);
        params[gid * 8 + 3] = 1.0f / (2.0f * sy * sy + 1e-8f);
        params[gid * 8 + 4] = 1.0f / (2.0f * sr * sr + 1e-8f);
        params[gid * 8 + 5] = R * R;
        params[gid * 8 + 6] = 0.0f;
        params[gid * 8 + 7] = 0.0f;
    }
}

__global__ __launch_bounds__(256) void jbu_kernel(
    const float* __restrict__ guide,  // [3][512][512]
    const float* __restrict__ ws,
    float* __restrict__ out)          // [128][512][512]
{
    const float* params = ws;
    const float* glr    = ws + 8192;
    const float* featT  = ws + 12288;

    const int cell  = blockIdx.x;        // 0..1023
    const int cellU = cell >> 5;
    const int cellV = cell & 31;
    const int px = threadIdx.x & 15;
    const int py = threadIdx.x >> 4;
    const int y = cellU * 16 + py;
    const int x = cellV * 16 + px;

    const float cos_t = params[cell * 8 + 0];
    const float sin_t = params[cell * 8 + 1];
    const float i2sx  = params[cell * 8 + 2];
    const float i2sy  = params[cell * 8 + 3];
    const float i2sr  = params[cell * 8 + 4];
    const float Rsq   = params[cell * 8 + 5];

    const float g0 = guide[0 * (HH * WH) + y * WH + x];
    const float g1 = guide[1 * (HH * WH) + y * WH + x];
    const float g2 = guide[2 * (HH * WH) + y * WH + x];

    const float fx = (float)x;
    const float fy = (float)y;

    float w[81];
    float den = 0.0f;
    #pragma unroll
    for (int dy = -4; dy <= 4; ++dy) {
        #pragma unroll
        for (int dx = -4; dx <= 4; ++dx) {
            const int k = (dy + 4) * 9 + (dx + 4);
            const float r2 = (float)(dy * dy + dx * dx);
            if (r2 <= Rsq) {   // wave-uniform branch
                const int ui = min(max(cellU + dy, 0), HL - 1);
                const int vi = min(max(cellV + dx, 0), WL - 1);
                const float cdx = (fx - ((float)(vi * 16) + 7.5f)) * 0.0625f;
                const float cdy = (fy - ((float)(ui * 16) + 7.5f)) * 0.0625f;
                const float a =  cdx * cos_t + cdy * sin_t;
                const float b =  cdy * cos_t - cdx * sin_t;
                const int nc = ui * 32 + vi;
                const float d0 = g0 - glr[nc * 4 + 0];
                const float d1 = g1 - glr[nc * 4 + 1];
                const float d2 = g2 - glr[nc * 4 + 2];
                const float gd = d0 * d0 + d1 * d1 + d2 * d2;
                const float lw = -(a * a) * i2sx - (b * b) * i2sy - gd * i2sr;
                const float wv = __expf(lw);
                w[k] = wv;
                den += wv;
            } else {
                w[k] = 0.0f;
            }
        }
    }

    const float inv = 1.0f / fmaxf(den, 1e-8f);
    #pragma unroll
    for (int kk = 0; kk < 81; ++kk) w[kk] *= inv;

    const int opix = y * WH + x;
    for (int c0 = 0; c0 < CF; c0 += 8) {
        float acc[8] = {0.f, 0.f, 0.f, 0.f, 0.f, 0.f, 0.f, 0.f};
        #pragma unroll
        for (int dy = -4; dy <= 4; ++dy) {
            #pragma unroll
            for (int dx = -4; dx <= 4; ++dx) {
                const int k = (dy + 4) * 9 + (dx + 4);
                const float r2 = (float)(dy * dy + dx * dx);
                if (r2 <= Rsq) {   // same uniform prune as above
                    const int ui = min(max(cellU + dy, 0), HL - 1);
                    const int vi = min(max(cellV + dx, 0), WL - 1);
                    const float* fp = featT + (ui * 32 + vi) * 128 + c0;  // wave-uniform -> s_load
                    const float wv = w[k];
                    #pragma unroll
                    for (int cc = 0; cc < 8; ++cc)
                        acc[cc] = fmaf(wv, fp[cc], acc[cc]);
                }
            }
        }
        #pragma unroll
        for (int cc = 0; cc < 8; ++cc)
            out[(c0 + cc) * (HH * WH) + opix] = acc[cc];
    }
}

extern "C" void kernel_launch(void* const* d_in, const int* in_sizes, int n_in,
                              void* d_out, int out_size, void* d_ws, size_t ws_size,
                              hipStream_t stream) {
    const float* feat   = (const float*)d_in[0];
    const float* guide  = (const float*)d_in[1];
    const float* sx_raw = (const float*)d_in[2];
    const float* sy_raw = (const float*)d_in[3];
    const float* th_raw = (const float*)d_in[4];
    const float* sr_raw = (const float*)d_in[5];
    float* out = (float*)d_out;
    float* ws  = (float*)d_ws;

    prep_kernel<<<512, 256, 0, stream>>>(feat, guide, sx_raw, sy_raw, th_raw, sr_raw, ws);
    jbu_kernel<<<1024, 256, 0, stream>>>(guide, ws, out);
}

// Round 2
// 72.976 us; speedup vs baseline: 11.3279x; 11.3279x over previous
//
#include <hip/hip_runtime.h>
#include <math.h>

#define HL 32
#define WL 32
#define HH 512
#define WH 512
#define CF 128
#define L2E 1.44269504f
#define PI_F 3.14159265358979323846f

// ws layout (floats):
//   glr:   [1024][4]   at offset 0      (guide_lr per cell, 3 ch + pad)
//   featT: [1024][128] at offset 4096   (feat transposed to cell-major)

__global__ __launch_bounds__(256) void prep_kernel(
    const float* __restrict__ feat,   // [128][32][32]
    const float* __restrict__ guide,  // [3][512][512]
    float* __restrict__ ws)
{
    const int gid = blockIdx.x * 256 + threadIdx.x;
    float* glr   = ws;            // [1024][4]
    float* featT = ws + 4096;     // [1024][128]

    if (gid < 1024 * 128) {
        const int cell = gid >> 7;
        const int c    = gid & 127;
        featT[gid] = feat[c * 1024 + cell];
    }
    if (gid < 1024) {
        const int u = gid >> 5, v = gid & 31;
        // bilinear downsample at SCALE=16 == 2x2 average at (16u+7, 16v+7)
        const int y0 = u * 16 + 7, x0 = v * 16 + 7;
        #pragma unroll
        for (int ch = 0; ch < 3; ++ch) {
            const float* g = guide + ch * (HH * WH);
            const float s = g[y0 * WH + x0] + g[y0 * WH + x0 + 1]
                          + g[(y0 + 1) * WH + x0] + g[(y0 + 1) * WH + x0 + 1];
            glr[gid * 4 + ch] = 0.25f * s;
        }
        glr[gid * 4 + 3] = 0.0f;
    }
}

// grid: 2048 blocks = 512 cell-pairs x 4 channel-quarters, 256 threads.
// block covers 2 horizontally adjacent cells (32x16 px) x 32 channels.
// thread = 2 pixels (rows r, r+8 of same column) x 32 channels.
__global__ __launch_bounds__(256, 4) void jbu_kernel(
    const float* __restrict__ guide,
    const float* __restrict__ sx_raw,
    const float* __restrict__ sy_raw,
    const float* __restrict__ th_raw,
    const float* __restrict__ sr_raw,
    const float* __restrict__ ws,
    float* __restrict__ out)
{
    const float* glr   = ws;
    const float* featT = ws + 4096;

    __shared__ __align__(16) float coef[2][656];     // [cell][8 hdr + 81*8]
    __shared__ __align__(16) float feat_lds[90 * 32];
    __shared__ int flg[192];

    const int tid  = threadIdx.x;
    const int bid  = blockIdx.x;
    const int q    = bid & 3;        // channel quarter
    const int pair = bid >> 2;
    const int baseU = pair >> 4;
    const int baseV = (pair & 15) << 1;

    // ---- stage feat union: 90 cells (9 rows x 10 cols) x 32 ch ----
    for (int s = tid; s < 90 * 32; s += 256) {
        const int slot = s >> 5, c = s & 31;
        const int su = slot / 10, sv = slot - su * 10;
        const int ui = min(max(baseU - 4 + su, 0), HL - 1);
        const int vi = min(max(baseV - 4 + sv, 0), WL - 1);
        feat_lds[s] = featT[(ui * 32 + vi) * 128 + q * 32 + c];
    }

    // ---- build per-cell coefficient tables (2 cells x 81 offsets) ----
    float e_K = 0.f, e_A = 0.f, e_B = 0.f, e_G0 = 0.f, e_G1 = 0.f, e_G2 = 0.f, e_nc = 0.f;
    int cs = 0, kk = 0, active = 0;
    if (tid < 162) {
        cs = (tid >= 81) ? 1 : 0;
        kk = tid - cs * 81;
        const int cellU = baseU, cellV = baseV + cs;
        const int cell = cellU * 32 + cellV;
        const float sx = fmaxf(__expf(sx_raw[cell]), 1e-6f);
        const float sy = fmaxf(__expf(sy_raw[cell]), 1e-6f);
        const float th = PI_F * tanhf(th_raw[cell]);
        const float sr = fmaxf(__expf(sr_raw[cell]), 1e-6f);
        const float R  = fminf(fmaxf(2.0f * fmaxf(sx, sy), 1.0f), 4.0f);
        const float Rsq = R * R;
        const float cth = cosf(th), sth = sinf(th);
        const float i2sx = 1.0f / (2.0f * sx * sx + 1e-8f);
        const float i2sy = 1.0f / (2.0f * sy * sy + 1e-8f);
        const float i2sr = 1.0f / (2.0f * sr * sr + 1e-8f);
        const int dyi = kk / 9 - 4;
        const int dxi = kk - (kk / 9) * 9 - 4;
        const int r2 = dyi * dyi + dxi * dxi;
        active = ((float)r2 <= Rsq) ? 1 : 0;
        const int ui = min(max(cellU + dyi, 0), HL - 1);
        const int vi = min(max(cellV + dxi, 0), WL - 1);
        const float rk = (float)(vi - cellV);
        const float tk = (float)(ui - cellU);
        const float ak = rk * cth + tk * sth;
        const float bk = tk * cth - rk * sth;
        const float gl0 = glr[(ui * 32 + vi) * 4 + 0];
        const float gl1 = glr[(ui * 32 + vi) * 4 + 1];
        const float gl2 = glr[(ui * 32 + vi) * 4 + 2];
        e_K = -(ak * ak * i2sx + bk * bk * i2sy
                + (gl0 * gl0 + gl1 * gl1 + gl2 * gl2) * i2sr) * L2E;
        e_A = 2.0f * ak * i2sx * L2E;
        e_B = 2.0f * bk * i2sy * L2E;
        e_G0 = 2.0f * gl0 * i2sr * L2E;
        e_G1 = 2.0f * gl1 * i2sr * L2E;
        e_G2 = 2.0f * gl2 * i2sr * L2E;
        e_nc = __int_as_float(ui * 10 + vi);
        flg[tid] = active;
        if (kk == 0) {
            coef[cs][0] = cth; coef[cs][1] = sth;
            coef[cs][2] = i2sx * L2E; coef[cs][3] = i2sy * L2E; coef[cs][4] = i2sr * L2E;
        }
    }
    __syncthreads();
    // deterministic exclusive scan (1 thread per cell)
    if (tid < 2) {
        int n = 0;
        for (int j = 0; j < 81; ++j) {
            const int f = flg[tid * 81 + j];
            flg[tid * 81 + j] = n;
            n += f;
        }
        coef[tid][5] = __int_as_float(n);
    }
    __syncthreads();
    // pad all 81 slots (exp2(-1e30) == 0)
    if (tid < 162) {
        float* e = &coef[cs][8 + kk * 8];
        e[0] = -1e30f; e[1] = 0.f; e[2] = 0.f; e[3] = 0.f;
        e[4] = 0.f; e[5] = 0.f;
        e[6] = __int_as_float(baseU * 10 + baseV + cs);
        e[7] = 0.f;
    }
    __syncthreads();
    if (tid < 162 && active) {
        float* e = &coef[cs][8 + flg[tid] * 8];
        e[0] = e_K; e[1] = e_A; e[2] = e_B; e[3] = e_G0;
        e[4] = e_G1; e[5] = e_G2; e[6] = e_nc; e[7] = 0.f;
    }
    __syncthreads();

    // ---- main accumulation ----
    const int px = tid & 31;
    const int r  = tid >> 5;           // 0..7
    const int cellSel = px >> 4;
    const int x  = baseV * 16 + px;
    const int y0 = baseU * 16 + r;
    const int y1 = y0 + 8;

    const float cth  = coef[cellSel][0];
    const float sth  = coef[cellSel][1];
    const float i2sxl = coef[cellSel][2];
    const float i2syl = coef[cellSel][3];
    const float i2srl = coef[cellSel][4];
    const int nact = max(__float_as_int(coef[0][5]), __float_as_int(coef[1][5]));
    const int C = baseU * 10 + baseV - 44;   // idx = nc - C

    const float qd = ((float)x - ((float)((baseV + cellSel) * 16) + 7.5f)) * 0.0625f;
    const float p0 = ((float)y0 - ((float)(baseU * 16) + 7.5f)) * 0.0625f;
    const float p1 = p0 + 0.5f;
    const float a00 = qd * cth + p0 * sth, b00 = p0 * cth - qd * sth;
    const float a01 = qd * cth + p1 * sth, b01 = p1 * cth - qd * sth;

    const int o0 = y0 * WH + x;
    const int o1 = y1 * WH + x;
    const float g00 = guide[0 * (HH * WH) + o0];
    const float g01 = guide[1 * (HH * WH) + o0];
    const float g02 = guide[2 * (HH * WH) + o0];
    const float g10 = guide[0 * (HH * WH) + o1];
    const float g11 = guide[1 * (HH * WH) + o1];
    const float g12 = guide[2 * (HH * WH) + o1];

    const float P0 = -(a00 * a00 * i2sxl + b00 * b00 * i2syl
                       + (g00 * g00 + g01 * g01 + g02 * g02) * i2srl);
    const float P1 = -(a01 * a01 * i2sxl + b01 * b01 * i2syl
                       + (g10 * g10 + g11 * g11 + g12 * g12) * i2srl);

    float acc0[32], acc1[32];
    #pragma unroll
    for (int c = 0; c < 32; ++c) { acc0[c] = 0.f; acc1[c] = 0.f; }
    float den0 = 0.f, den1 = 0.f;

    const float4* cf = (const float4*)&coef[cellSel][8];
    for (int k = 0; k < nact; ++k) {
        const float4 ca = cf[k * 2];       // K, A, B, G0
        const float4 cb = cf[k * 2 + 1];   // G1, G2, nc, pad
        const int idx = __float_as_int(cb.z) - C;

        float lw0 = P0 + ca.x;
        lw0 = fmaf(a00, ca.y, lw0);
        lw0 = fmaf(b00, ca.z, lw0);
        lw0 = fmaf(g00, ca.w, lw0);
        lw0 = fmaf(g01, cb.x, lw0);
        lw0 = fmaf(g02, cb.y, lw0);
        float lw1 = P1 + ca.x;
        lw1 = fmaf(a01, ca.y, lw1);
        lw1 = fmaf(b01, ca.z, lw1);
        lw1 = fmaf(g10, ca.w, lw1);
        lw1 = fmaf(g11, cb.x, lw1);
        lw1 = fmaf(g12, cb.y, lw1);
        const float w0 = __builtin_amdgcn_exp2f(lw0);
        const float w1 = __builtin_amdgcn_exp2f(lw1);
        den0 += w0; den1 += w1;

        const float4* fp = (const float4*)&feat_lds[idx * 32];
        #pragma unroll
        for (int g8 = 0; g8 < 8; ++g8) {
            const float4 f = fp[g8];
            acc0[g8 * 4 + 0] = fmaf(w0, f.x, acc0[g8 * 4 + 0]);
            acc0[g8 * 4 + 1] = fmaf(w0, f.y, acc0[g8 * 4 + 1]);
            acc0[g8 * 4 + 2] = fmaf(w0, f.z, acc0[g8 * 4 + 2]);
            acc0[g8 * 4 + 3] = fmaf(w0, f.w, acc0[g8 * 4 + 3]);
            acc1[g8 * 4 + 0] = fmaf(w1, f.x, acc1[g8 * 4 + 0]);
            acc1[g8 * 4 + 1] = fmaf(w1, f.y, acc1[g8 * 4 + 1]);
            acc1[g8 * 4 + 2] = fmaf(w1, f.z, acc1[g8 * 4 + 2]);
            acc1[g8 * 4 + 3] = fmaf(w1, f.w, acc1[g8 * 4 + 3]);
        }
    }

    const float inv0 = 1.0f / fmaxf(den0, 1e-8f);
    const float inv1 = 1.0f / fmaxf(den1, 1e-8f);
    #pragma unroll
    for (int c = 0; c < 32; ++c) {
        out[(q * 32 + c) * (HH * WH) + o0] = acc0[c] * inv0;
        out[(q * 32 + c) * (HH * WH) + o1] = acc1[c] * inv1;
    }
}

extern "C" void kernel_launch(void* const* d_in, const int* in_sizes, int n_in,
                              void* d_out, int out_size, void* d_ws, size_t ws_size,
                              hipStream_t stream) {
    const float* feat   = (const float*)d_in[0];
    const float* guide  = (const float*)d_in[1];
    const float* sx_raw = (const float*)d_in[2];
    const float* sy_raw = (const float*)d_in[3];
    const float* th_raw = (const float*)d_in[4];
    const float* sr_raw = (const float*)d_in[5];
    float* out = (float*)d_out;
    float* ws  = (float*)d_ws;

    prep_kernel<<<512, 256, 0, stream>>>(feat, guide, ws);
    jbu_kernel<<<2048, 256, 0, stream>>>(guide, sx_raw, sy_raw, th_raw, sr_raw, ws, out);
}

// Round 3
// 42.579 us; speedup vs baseline: 19.4148x; 1.7139x over previous
//
#include <hip/hip_runtime.h>
#include <math.h>

#define HH 512
#define WH 512
#define L2E 1.44269504f
#define PI_F 3.14159265358979323846f
#define FTK 104   // padded K stride in shorts (208 B) -> conflict-free ds_read_b128

typedef __attribute__((ext_vector_type(8))) short short8v;
typedef __attribute__((ext_vector_type(4))) float float4v;

// ws layout:
//   glr:   [1024][4] f32  at float offset 0     (16 KB)
//   featT: [1024][128] bf16 at float offset 4096 (256 KB), cell-major, ch contiguous

__global__ __launch_bounds__(256) void prep_kernel(
    const float* __restrict__ feat,   // [128][32][32]
    const float* __restrict__ guide,  // [3][512][512]
    float* __restrict__ ws)
{
    const int gid = blockIdx.x * 256 + threadIdx.x;
    float* glr = ws;
    unsigned short* featT = (unsigned short*)(ws + 4096);
    if (gid < 131072) {
        const int cell = gid >> 7;
        const int c    = gid & 127;
        const float v  = feat[c * 1024 + cell];
        const unsigned int b = __float_as_uint(v);
        featT[gid] = (unsigned short)((b + 0x7FFFu + ((b >> 16) & 1u)) >> 16);  // rne bf16
    }
    if (gid < 1024) {
        const int u = gid >> 5, v = gid & 31;
        // bilinear downsample at SCALE=16 == 2x2 average at (16u+7, 16v+7)
        const int y0 = u * 16 + 7, x0 = v * 16 + 7;
        #pragma unroll
        for (int ch = 0; ch < 3; ++ch) {
            const float* g = guide + ch * (HH * WH);
            const float s = g[y0 * WH + x0] + g[y0 * WH + x0 + 1]
                          + g[(y0 + 1) * WH + x0] + g[(y0 + 1) * WH + x0 + 1];
            glr[gid * 4 + ch] = 0.25f * s;
        }
        glr[gid * 4 + 3] = 0.0f;
    }
}

// grid: 512 blocks = 512 cell-pairs; 512 threads = 8 waves.
// wave w: cell c2 = w>>2 of the pair, pixel rows (w&3)*4 .. +3 (each M-tile = one pixel row).
__global__ __launch_bounds__(512, 1) void jbu_kernel(
    const float* __restrict__ guide,
    const float* __restrict__ sx_raw,
    const float* __restrict__ sy_raw,
    const float* __restrict__ th_raw,
    const float* __restrict__ sr_raw,
    const float* __restrict__ ws,
    float* __restrict__ out)
{
    __shared__ __align__(16) unsigned short FT[2 * 128 * FTK];  // 53.2 KB, [cell][ch][k]
    __shared__ float tabK[192], tabA[192], tabB[192], tabG0[192], tabG1[192], tabG2[192];
    __shared__ float hdr[2][6];

    const float* glr = ws;
    const unsigned short* featT = (const unsigned short*)(ws + 4096);

    const int tid = threadIdx.x;
    const int u = blockIdx.x >> 4;
    const int v = (blockIdx.x & 15) << 1;

    // ---- per-cell coefficient tables (2 cells x 96 k-slots) ----
    if (tid < 192) {
        const int c2 = tid / 96;
        const int k  = tid - c2 * 96;
        const int cu = u, cv = v + c2;
        const int cell = cu * 32 + cv;
        const float sx = fmaxf(__expf(sx_raw[cell]), 1e-6f);
        const float sy = fmaxf(__expf(sy_raw[cell]), 1e-6f);
        const float thv = PI_F * tanhf(th_raw[cell]);
        const float sr = fmaxf(__expf(sr_raw[cell]), 1e-6f);
        const float R  = fminf(fmaxf(2.0f * fmaxf(sx, sy), 1.0f), 4.0f);
        const float cth = cosf(thv), sth = sinf(thv);
        const float i2sx = 1.0f / (2.0f * sx * sx + 1e-8f);
        const float i2sy = 1.0f / (2.0f * sy * sy + 1e-8f);
        const float i2sr = 1.0f / (2.0f * sr * sr + 1e-8f);
        if (k == 0) {
            hdr[c2][0] = cth; hdr[c2][1] = sth;
            hdr[c2][2] = i2sx * L2E; hdr[c2][3] = i2sy * L2E; hdr[c2][4] = i2sr * L2E;
        }
        const int k9 = k / 9;
        const int dy = k9 - 4, dx = k - k9 * 9 - 4;
        const int act = (k < 81) && ((float)(dy * dy + dx * dx) <= R * R);
        const int ui = min(max(cu + dy, 0), 31);
        const int vi = min(max(cv + dx, 0), 31);
        const float rk = (float)(vi - cv), tk = (float)(ui - cu);
        const float ak = rk * cth + tk * sth;
        const float bk = tk * cth - rk * sth;
        const float gl0 = glr[(ui * 32 + vi) * 4 + 0];
        const float gl1 = glr[(ui * 32 + vi) * 4 + 1];
        const float gl2 = glr[(ui * 32 + vi) * 4 + 2];
        tabK[tid]  = act ? -(ak * ak * i2sx + bk * bk * i2sy
                             + (gl0 * gl0 + gl1 * gl1 + gl2 * gl2) * i2sr) * L2E
                         : -1e30f;
        tabA[tid]  = 2.0f * ak * i2sx * L2E;
        tabB[tid]  = 2.0f * bk * i2sy * L2E;
        tabG0[tid] = 2.0f * gl0 * i2sr * L2E;
        tabG1[tid] = 2.0f * gl1 * i2sr * L2E;
        tabG2[tid] = 2.0f * gl2 * i2sr * L2E;
    }

    // ---- stage features k-major: FT[c2][ch][k] = featT[cell(c2,k)][ch], k fastest over lanes ----
    for (int s = tid; s < 3072; s += 512) {      // 2 c2 * 16 chgroups * 96 k
        const int k   = s % 96;
        const int cg  = (s / 96) & 15;
        const int c2s = s / 1536;
        unsigned short vals[8] = {0, 0, 0, 0, 0, 0, 0, 0};
        if (k < 81) {
            const int k9 = k / 9;
            const int dy = k9 - 4, dx = k - k9 * 9 - 4;
            const int ui = min(max(u + dy, 0), 31);
            const int vi = min(max(v + c2s + dx, 0), 31);
            *(uint4*)vals = *(const uint4*)(featT + (ui * 32 + vi) * 128 + cg * 8);
        }
        const int chb = c2s * 128 + cg * 8;
        #pragma unroll
        for (int j = 0; j < 8; ++j)
            FT[(chb + j) * FTK + k] = vals[j];
    }
    __syncthreads();

    // ---- per-wave setup ----
    const int wave = tid >> 6;
    const int lane = tid & 63;
    const int lg   = lane >> 4;       // k-group (A/B), x-group (C/D)
    const int pxx  = lane & 15;       // A row / B col
    const int c2   = wave >> 2;
    const int mtb  = (wave & 3) * 4;  // pixel-row base
    const int cv   = v + c2;

    const float cth = hdr[c2][0], sth = hdr[c2][1];
    const float i2sxl = hdr[c2][2], i2syl = hdr[c2][3], i2srl = hdr[c2][4];
    const float qd = ((float)pxx - 7.5f) * 0.0625f;

    float a0[4], b0[4], P[4], g0[4], g1[4], g2[4];
    #pragma unroll
    for (int mt = 0; mt < 4; ++mt) {
        const int y = u * 16 + mtb + mt;
        const int o = y * WH + cv * 16 + pxx;
        g0[mt] = guide[o];
        g1[mt] = guide[HH * WH + o];
        g2[mt] = guide[2 * HH * WH + o];
        const float pd = ((float)(mtb + mt) - 7.5f) * 0.0625f;
        a0[mt] = qd * cth + pd * sth;
        b0[mt] = pd * cth - qd * sth;
        P[mt] = -(a0[mt] * a0[mt] * i2sxl + b0[mt] * b0[mt] * i2syl
                  + (g0[mt] * g0[mt] + g1[mt] * g1[mt] + g2[mt] * g2[mt]) * i2srl);
    }

    // ---- weight gen directly into A fragments (lane: row=pxx, k=ks*32+lg*8+i) ----
    short8v Afrag[4][3];
    float den[4] = {0.f, 0.f, 0.f, 0.f};
    const int tb = c2 * 96;
    #pragma unroll
    for (int ks = 0; ks < 3; ++ks) {
        float cK[8], cA[8], cB[8], cG0[8], cG1[8], cG2[8];
        #pragma unroll
        for (int i = 0; i < 8; ++i) {
            const int k = tb + ks * 32 + lg * 8 + i;
            cK[i] = tabK[k];  cA[i] = tabA[k];  cB[i] = tabB[k];
            cG0[i] = tabG0[k]; cG1[i] = tabG1[k]; cG2[i] = tabG2[k];
        }
        #pragma unroll
        for (int mt = 0; mt < 4; ++mt) {
            short8v av;
            #pragma unroll
            for (int i = 0; i < 8; ++i) {
                float lw = P[mt] + cK[i];
                lw = fmaf(a0[mt], cA[i], lw);
                lw = fmaf(b0[mt], cB[i], lw);
                lw = fmaf(g0[mt], cG0[i], lw);
                lw = fmaf(g1[mt], cG1[i], lw);
                lw = fmaf(g2[mt], cG2[i], lw);
                const float w = __builtin_amdgcn_exp2f(lw);
                den[mt] += w;
                const unsigned int b = __float_as_uint(w);
                av[i] = (short)((b + 0x7FFFu + ((b >> 16) & 1u)) >> 16);
            }
            Afrag[mt][ks] = av;
        }
    }

    // ---- den: reduce over the 4 k-groups sharing pxx, then redistribute to C rows ----
    float invd[4][4];
    #pragma unroll
    for (int mt = 0; mt < 4; ++mt) {
        float d = den[mt];
        d += __shfl_xor(d, 16);
        d += __shfl_xor(d, 32);
        const float id = 1.0f / fmaxf(d, 1e-8f);
        #pragma unroll
        for (int r = 0; r < 4; ++r)
            invd[mt][r] = __shfl(id, lg * 4 + r);   // den of C-row lg*4+r
    }

    // ---- MFMA + store, two channel halves ----
    #pragma unroll
    for (int q = 0; q < 2; ++q) {
        short8v Bf[4][3];
        #pragma unroll
        for (int nt = 0; nt < 4; ++nt) {
            #pragma unroll
            for (int ks = 0; ks < 3; ++ks) {
                const int ch = q * 64 + nt * 16 + pxx;
                Bf[nt][ks] = *(const short8v*)&FT[(c2 * 128 + ch) * FTK + ks * 32 + lg * 8];
            }
        }
        #pragma unroll
        for (int mt = 0; mt < 4; ++mt) {
            float4v acc[4] = {{0.f,0.f,0.f,0.f}, {0.f,0.f,0.f,0.f},
                              {0.f,0.f,0.f,0.f}, {0.f,0.f,0.f,0.f}};
            #pragma unroll
            for (int nt = 0; nt < 4; ++nt)
                #pragma unroll
                for (int ks = 0; ks < 3; ++ks)
                    acc[nt] = __builtin_amdgcn_mfma_f32_16x16x32_bf16(
                        Afrag[mt][ks], Bf[nt][ks], acc[nt], 0, 0, 0);
            const int y = u * 16 + mtb + mt;
            const size_t pix = (size_t)(y * WH + cv * 16 + lg * 4);
            #pragma unroll
            for (int nt = 0; nt < 4; ++nt) {
                const int ch = q * 64 + nt * 16 + pxx;
                float4v res;
                res[0] = acc[nt][0] * invd[mt][0];
                res[1] = acc[nt][1] * invd[mt][1];
                res[2] = acc[nt][2] * invd[mt][2];
                res[3] = acc[nt][3] * invd[mt][3];
                *(float4v*)(out + (size_t)ch * (HH * WH) + pix) = res;
            }
        }
    }
}

extern "C" void kernel_launch(void* const* d_in, const int* in_sizes, int n_in,
                              void* d_out, int out_size, void* d_ws, size_t ws_size,
                              hipStream_t stream) {
    const float* feat   = (const float*)d_in[0];
    const float* guide  = (const float*)d_in[1];
    const float* sx_raw = (const float*)d_in[2];
    const float* sy_raw = (const float*)d_in[3];
    const float* th_raw = (const float*)d_in[4];
    const float* sr_raw = (const float*)d_in[5];
    float* out = (float*)d_out;
    float* ws  = (float*)d_ws;

    prep_kernel<<<512, 256, 0, stream>>>(feat, guide, ws);
    jbu_kernel<<<512, 512, 0, stream>>>(guide, sx_raw, sy_raw, th_raw, sr_raw, ws, out);
}